// Round 5
// baseline (233.157 us; speedup 1.0000x reference)
//
#include <hip/hip_runtime.h>

// MoE_52037823758984: out[i] = x[i] @ W_{route[i]}^T + b_{route[i]}
// N = 2,097,152 tokens, D = 10, all f32 (route int32).
//
// R5: shorten the per-wave serial path (latency-bound regime; R2/R4 counters
// show nothing saturated: VALU<30%, LDS conflicts 0, HBM 27%).
//  - R2 shell: 4096 blocks x 256, one 512-row chunk per block (block
//    turnover = natural pipelining; explicit pipelining regressed in R4).
//  - Input transpose via wave-private LDS (proven conflict-free).
//  - Packed f32 math: (row0,row1) pairs in float2 accumulators ->
//    v_pk_fma_f32, halving FMA issue on the critical path.
//  - NO output LDS trip: lane's rows 2L,2L+1 are 80 contiguous bytes ->
//    direct nontemporal dwordx4 stores (fire-and-forget; L2 sector-merges,
//    R1 showed no HBM write amplification from strided stores).

#define BLOCK 256
#define D 10
#define WAVE_ROWS 128              // rows per wave
#define F4_PER_WAVE 320            // 128*10/4
#define ROWS_PER_BLOCK 512         // 4 waves

typedef float f4 __attribute__((ext_vector_type(4)));
typedef float f2 __attribute__((ext_vector_type(2)));

__global__ __launch_bounds__(BLOCK) void moe_kernel(
    const float* __restrict__ x,
    const float* __restrict__ W1,
    const float* __restrict__ b1,
    const float* __restrict__ W2,
    const float* __restrict__ b2,
    const int*   __restrict__ route,
    float*       __restrict__ out,
    int n)
{
    __shared__ f4 lds[(BLOCK / 64) * F4_PER_WAVE];  // 20 KB

    const int lane = threadIdx.x & 63;
    const int wave = threadIdx.x >> 6;
    f4* __restrict__ wlds = lds + wave * F4_PER_WAVE;

    const long long rowbase =
        ((long long)blockIdx.x * (BLOCK / 64) + wave) * WAVE_ROWS;

    if (rowbase + WAVE_ROWS <= n) {
        // ---------- coalesced loads: 5 f4/lane + route int2 ----------
        const f4* __restrict__ xv = (const f4*)(x + rowbase * D);
        f4 bx[5];
        #pragma unroll
        for (int j = 0; j < 5; ++j)
            bx[j] = xv[j * 64 + lane];
        const int2 rt = ((const int2*)(route + rowbase))[lane];

        // ---------- LDS transpose in ----------
        #pragma unroll
        for (int j = 0; j < 5; ++j)
            wlds[j * 64 + lane] = bx[j];
        __builtin_amdgcn_wave_barrier();

        // lane's 2 rows (20 consecutive floats), conflict-free b128 reads
        float xf[2 * D];
        #pragma unroll
        for (int j = 0; j < 5; ++j) {
            f4 t = wlds[lane * 5 + j];
            xf[4 * j + 0] = t.x; xf[4 * j + 1] = t.y;
            xf[4 * j + 2] = t.z; xf[4 * j + 3] = t.w;
        }

        // row-pair vectors: xp[k] = (row0[k], row1[k])
        f2 xp[D];
        #pragma unroll
        for (int k = 0; k < D; ++k)
            xp[k] = (f2){xf[k], xf[D + k]};

        // ---------- packed MLP: both experts, j-outer (low reg press.) ----
        float o0[D], o1[D];   // row0, row1 selected outputs
        #pragma unroll
        for (int j = 0; j < D; ++j) {
            f2 a0 = (f2){b1[j], b1[j]};
            f2 a1 = (f2){b2[j], b2[j]};
            #pragma unroll
            for (int k = 0; k < D; ++k) {
                const float w1 = W1[j * D + k];
                const float w2 = W2[j * D + k];
                a0 = __builtin_elementwise_fma(xp[k], (f2){w1, w1}, a0);
                a1 = __builtin_elementwise_fma(xp[k], (f2){w2, w2}, a1);
            }
            o0[j] = rt.x ? a1.x : a0.x;
            o1[j] = rt.y ? a1.y : a0.y;
        }

        // ---------- direct stores: 80 contiguous bytes per lane ----------
        // rows 2L,2L+1 live at out + rowbase*D + lane*20 (16B aligned)
        f4* __restrict__ ov = (f4*)(out + rowbase * D) + lane * 5;
        f4 t0 = (f4){o0[0], o0[1], o0[2], o0[3]};
        f4 t1 = (f4){o0[4], o0[5], o0[6], o0[7]};
        f4 t2 = (f4){o0[8], o0[9], o1[0], o1[1]};
        f4 t3 = (f4){o1[2], o1[3], o1[4], o1[5]};
        f4 t4 = (f4){o1[6], o1[7], o1[8], o1[9]};
        __builtin_nontemporal_store(t0, ov + 0);
        __builtin_nontemporal_store(t1, ov + 1);
        __builtin_nontemporal_store(t2, ov + 2);
        __builtin_nontemporal_store(t3, ov + 3);
        __builtin_nontemporal_store(t4, ov + 4);
    } else {
        // ---------- tail path (not hit for N=2097152) ----------
        for (int r = 0; r < 2; ++r) {
            const long long row = rowbase + lane * 2 + r;
            if (row < n) {
                const int sel = route[row];
                for (int j = 0; j < D; ++j) {
                    float y0 = b1[j];
                    float y1 = b2[j];
                    for (int k = 0; k < D; ++k) {
                        const float xk = x[row * D + k];
                        y0 = fmaf(xk, W1[j * D + k], y0);
                        y1 = fmaf(xk, W2[j * D + k], y1);
                    }
                    out[row * D + j] = sel ? y1 : y0;
                }
            }
        }
    }
}

extern "C" void kernel_launch(void* const* d_in, const int* in_sizes, int n_in,
                              void* d_out, int out_size, void* d_ws, size_t ws_size,
                              hipStream_t stream) {
    const float* x     = (const float*)d_in[0];
    const float* W1    = (const float*)d_in[1];
    const float* b1    = (const float*)d_in[2];
    const float* W2    = (const float*)d_in[3];
    const float* b2    = (const float*)d_in[4];
    const int*   route = (const int*)d_in[5];
    float*       out   = (float*)d_out;

    const int n = in_sizes[5];  // N tokens (route length)
    const int blocks = (n + ROWS_PER_BLOCK - 1) / ROWS_PER_BLOCK;  // 4096

    moe_kernel<<<blocks, BLOCK, 0, stream>>>(x, W1, b1, W2, b2, route, out, n);
}

// Round 6
// 163.466 us; speedup vs baseline: 1.4263x; 1.4263x over previous
//
#include <hip/hip_runtime.h>

// MoE_52037823758984: out[i] = x[i] @ W_{route[i]}^T + b_{route[i]}
// N = 2,097,152 tokens, D = 10, all f32 (route int32).
//
// R6 = R2's proven I/O shell + R5's proven packed compute.
//  - LDS round-trip BOTH directions; global loads and stores are
//    lane-contiguous 1 KB/instruction. WRITE_SIZE was clean (82 MB) in
//    R2/R4; R5 proved nontemporal+strided amplifies writes 2.65x -> nt is
//    used ONLY on fully-coalesced stores (proven clean in R4).
//  - Packed f32 math: (row0,row1) in float2 accumulators -> v_pk_fma_f32
//    (R5 measured VALUBusy 5.8%).
//  - 4096 blocks x 256, one 512-row chunk per block; block turnover is the
//    pipelining (explicit persistence regressed in R4).

#define BLOCK 256
#define D 10
#define WAVE_ROWS 128              // rows per wave
#define F4_PER_WAVE 320            // 128*10/4
#define ROWS_PER_BLOCK 512         // 4 waves

typedef float f4 __attribute__((ext_vector_type(4)));
typedef float f2 __attribute__((ext_vector_type(2)));

__global__ __launch_bounds__(BLOCK) void moe_kernel(
    const float* __restrict__ x,
    const float* __restrict__ W1,
    const float* __restrict__ b1,
    const float* __restrict__ W2,
    const float* __restrict__ b2,
    const int*   __restrict__ route,
    float*       __restrict__ out,
    int n)
{
    __shared__ f4 lds[(BLOCK / 64) * F4_PER_WAVE];  // 20 KB

    const int lane = threadIdx.x & 63;
    const int wave = threadIdx.x >> 6;
    f4* __restrict__ wlds = lds + wave * F4_PER_WAVE;

    const long long rowbase =
        ((long long)blockIdx.x * (BLOCK / 64) + wave) * WAVE_ROWS;

    if (rowbase + WAVE_ROWS <= n) {
        // ---------- coalesced loads: 5 f4/lane + route int2 ----------
        const f4* __restrict__ xv = (const f4*)(x + rowbase * D);
        f4 bx[5];
        #pragma unroll
        for (int j = 0; j < 5; ++j)
            bx[j] = xv[j * 64 + lane];
        const int2 rt = ((const int2*)(route + rowbase))[lane];

        // ---------- LDS transpose in ----------
        #pragma unroll
        for (int j = 0; j < 5; ++j)
            wlds[j * 64 + lane] = bx[j];
        __builtin_amdgcn_wave_barrier();

        // lane's 2 rows (20 consecutive floats), conflict-free b128 reads
        float xf[2 * D];
        #pragma unroll
        for (int j = 0; j < 5; ++j) {
            f4 t = wlds[lane * 5 + j];
            xf[4 * j + 0] = t.x; xf[4 * j + 1] = t.y;
            xf[4 * j + 2] = t.z; xf[4 * j + 3] = t.w;
        }

        // row-pair vectors: xp[k] = (row0[k], row1[k])
        f2 xp[D];
        #pragma unroll
        for (int k = 0; k < D; ++k)
            xp[k] = (f2){xf[k], xf[D + k]};

        // ---------- packed MLP: both experts, route-select ----------
        float o0[D], o1[D];
        #pragma unroll
        for (int j = 0; j < D; ++j) {
            f2 a0 = (f2){b1[j], b1[j]};
            f2 a1 = (f2){b2[j], b2[j]};
            #pragma unroll
            for (int k = 0; k < D; ++k) {
                const float w1 = W1[j * D + k];
                const float w2 = W2[j * D + k];
                a0 = __builtin_elementwise_fma(xp[k], (f2){w1, w1}, a0);
                a1 = __builtin_elementwise_fma(xp[k], (f2){w2, w2}, a1);
            }
            o0[j] = rt.x ? a1.x : a0.x;
            o1[j] = rt.y ? a1.y : a0.y;
        }

        // ---------- LDS transpose out (lane-private slots, in-order) ----
        __builtin_amdgcn_wave_barrier();  // keep behind the ds_reads above
        {
            f4 t0 = (f4){o0[0], o0[1], o0[2], o0[3]};
            f4 t1 = (f4){o0[4], o0[5], o0[6], o0[7]};
            f4 t2 = (f4){o0[8], o0[9], o1[0], o1[1]};
            f4 t3 = (f4){o1[2], o1[3], o1[4], o1[5]};
            f4 t4 = (f4){o1[6], o1[7], o1[8], o1[9]};
            wlds[lane * 5 + 0] = t0;
            wlds[lane * 5 + 1] = t1;
            wlds[lane * 5 + 2] = t2;
            wlds[lane * 5 + 3] = t3;
            wlds[lane * 5 + 4] = t4;
        }
        __builtin_amdgcn_wave_barrier();

        // ---------- coalesced nontemporal stores (1 KB/instr, clean) ----
        f4* __restrict__ ov = (f4*)(out + rowbase * D);
        #pragma unroll
        for (int j = 0; j < 5; ++j) {
            f4 t = wlds[j * 64 + lane];
            __builtin_nontemporal_store(t, &ov[j * 64 + lane]);
        }
    } else {
        // ---------- tail path (not hit for N=2097152) ----------
        for (int r = 0; r < 2; ++r) {
            const long long row = rowbase + lane * 2 + r;
            if (row < n) {
                const int sel = route[row];
                for (int j = 0; j < D; ++j) {
                    float y0 = b1[j];
                    float y1 = b2[j];
                    for (int k = 0; k < D; ++k) {
                        const float xk = x[row * D + k];
                        y0 = fmaf(xk, W1[j * D + k], y0);
                        y1 = fmaf(xk, W2[j * D + k], y1);
                    }
                    out[row * D + j] = sel ? y1 : y0;
                }
            }
        }
    }
}

extern "C" void kernel_launch(void* const* d_in, const int* in_sizes, int n_in,
                              void* d_out, int out_size, void* d_ws, size_t ws_size,
                              hipStream_t stream) {
    const float* x     = (const float*)d_in[0];
    const float* W1    = (const float*)d_in[1];
    const float* b1    = (const float*)d_in[2];
    const float* W2    = (const float*)d_in[3];
    const float* b2    = (const float*)d_in[4];
    const int*   route = (const int*)d_in[5];
    float*       out   = (float*)d_out;

    const int n = in_sizes[5];  // N tokens (route length)
    const int blocks = (n + ROWS_PER_BLOCK - 1) / ROWS_PER_BLOCK;  // 4096

    moe_kernel<<<blocks, BLOCK, 0, stream>>>(x, W1, b1, W2, b2, route, out, n);
}